// Round 22
// baseline (514.873 us; speedup 1.0000x reference)
//
#include <hip/hip_runtime.h>

#define TOK 8192
#define NE 64
#define DIM 4096
#define CAP 128
static const long long NCOMB_LL = (long long)TOK * NE * CAP;  // 67108864

// ---------------- kwarm: pull x into L3 with coalesced reads -----------------
// Read-only; asm keeps loads live (DCE rule #17). No numeric effect.
__global__ __launch_bounds__(256) void kwarm(const float* __restrict__ x) {
  long long i = (long long)blockIdx.x * 256 + threadIdx.x;
  const float4* p = (const float4*)x;             // 8388608 float4s
  float4 s = make_float4(0.f, 0.f, 0.f, 0.f);
  for (int it = 0; it < 16; ++it) {
    long long j = i + (long long)it * 524288LL;
    float4 v = p[j];
    s.x += v.x; s.y += v.y; s.z += v.z; s.w += v.w;
  }
  float t = s.x + s.y + s.z + s.w;
  asm volatile("" :: "v"(t));
}

// ---------------- k0: transpose w[64][4096] -> wt interleaved [k/4][64][4] ----
__global__ __launch_bounds__(256) void k0_wt(const float* __restrict__ w,
                                             float* __restrict__ wt) {
  int gid = blockIdx.x * 256 + threadIdx.x;       // 0..262143 = k*64 + e
  int e = gid & 63, k = gid >> 6;
  wt[(k >> 2) * 256 + e * 4 + (k & 3)] = w[e * DIM + k];
}

// ---------------- k1: split-K partial GEMM -> part[4][8192][64] --------------
// lane = expert. FROZEN SOURCE (validated passing rounds 3, 9, 11, 13, 15, 17
// with launch-bounds (256,2) — spill-free VGPR=68, realization stable across
// all container draws since r3; the (256,4) variant sits at the VGPR=64 spill
// boundary and proved toolchain-sensitive, 1/3 pass r18/r20/r21). Do not edit.
__global__ __launch_bounds__(256, 2) void k1_gemm(const float* __restrict__ x,
                                                  const float* __restrict__ wt,
                                                  float* __restrict__ part) {
  int tid = threadIdx.x;
  int lane = tid & 63;
  int wid = tid >> 6;
  int tile = blockIdx.x >> 2;                     // 0..255
  int ks = blockIdx.x & 3;                        // 0..3
  int tok0 = tile * 32 + wid * 8;
  int k0 = ks * 1024;
  float acc[8] = {0.f, 0.f, 0.f, 0.f, 0.f, 0.f, 0.f, 0.f};
  const float4* wt4 = (const float4*)wt + lane;
  for (int kc = k0; kc < k0 + 1024; kc += 32) {
    float4 wr[8];
#pragma unroll
    for (int j = 0; j < 8; ++j) wr[j] = wt4[((kc >> 2) + j) * 64];
#pragma unroll
    for (int t = 0; t < 8; ++t) {
      const float4* xp = (const float4*)(x + (long long)(tok0 + t) * DIM + kc);
      float4 xv[8];
#pragma unroll
      for (int j = 0; j < 8; ++j) xv[j] = xp[j];
#pragma unroll
      for (int j = 0; j < 8; ++j)
        acc[t] += xv[j].x * wr[j].x + xv[j].y * wr[j].y +
                  xv[j].z * wr[j].z + xv[j].w * wr[j].w;
    }
  }
#pragma unroll
  for (int t = 0; t < 8; ++t)
    part[((long long)ks * TOK + tok0 + t) * 64 + lane] = acc[t];
}

// ---------------- k1b: reduce split-K, softmax, argmax -----------------------
__global__ __launch_bounds__(256) void k1b(const float* __restrict__ part,
                                           int* __restrict__ eidx,
                                           float* __restrict__ gate,
                                           float* __restrict__ gpart) {
  int tid = threadIdx.x, lane = tid & 63, wid = tid >> 6;
  int blk = blockIdx.x;                           // 256 blocks x 32 tokens
  float gsum = 0.f;
  for (int i = 0; i < 8; ++i) {
    int tok = blk * 32 + wid * 8 + i;
    float v = part[(long long)tok * 64 + lane] +
              part[((long long)TOK + tok) * 64 + lane] +
              part[((long long)2 * TOK + tok) * 64 + lane] +
              part[((long long)3 * TOK + tok) * 64 + lane];
    float m = v;
#pragma unroll
    for (int o = 32; o > 0; o >>= 1) m = fmaxf(m, __shfl_xor(m, o));
    float p = expf(v - m);
    float s = p;
#pragma unroll
    for (int o = 32; o > 0; o >>= 1) s += __shfl_xor(s, o);
    float g = p / s;                              // softmax value (lane=expert)
    float gm = g;
#pragma unroll
    for (int o = 32; o > 0; o >>= 1) gm = fmaxf(gm, __shfl_xor(gm, o));
    unsigned long long bal = __ballot(g == gm);
    int am = __ffsll((unsigned long long)bal) - 1; // first (lowest) max index
    float gv = __shfl(g, am);
    if (lane == 0) { eidx[tok] = am; gate[tok] = gv; }
    gsum += g;
  }
  __shared__ float red[4][64];
  red[wid][lane] = gsum;
  __syncthreads();
  if (wid == 0) {
    float t = red[0][lane] + red[1][lane] + red[2][lane] + red[3][lane];
    gpart[blk * 64 + lane] = t;                   // per-block gate sums (det.)
  }
}

// ---------------- k2: per-expert ordered positions + l_aux (1 block) ---------
// r13 re-roll of the r12 rewrite (logic unchanged, decls permuted): per-wave
// LDS-atomic-OR builds each batch's expert mask in 3 DS ops (vs 64 ballots);
// masks cached in registers kill phase-2 ballots; gpart sum parallelized
// across 16 waves. Mask/position integers bit-identical to the ballot
// version; only l_aux's f32 add order changes (tolerance 2e-2).
__global__ __launch_bounds__(1024) void k2(const int* __restrict__ eidx,
                                           const float* __restrict__ gpart,
                                           int* __restrict__ code,
                                           float* __restrict__ out0) {
  __shared__ unsigned int mw[16][64][2];          // per-wave expert masks
  __shared__ float gred[16][64];
  __shared__ unsigned int cnts[16][64];
  __shared__ unsigned int base[16][64];
  int tid = threadIdx.x, lane = tid & 63, wid = tid >> 6;
  int e[8];
  unsigned long long msave[8];
  unsigned int cnt = 0;                           // lane = expert
#pragma unroll
  for (int b = 0; b < 8; ++b) {
    int tok = wid * 512 + b * 64 + lane;
    int ee = eidx[tok];
    e[b] = ee;
    mw[wid][lane][0] = 0u;                        // own slot: no race
    mw[wid][lane][1] = 0u;
    atomicOr(&mw[wid][ee][lane >> 5], 1u << (lane & 31));  // wave-private; DS in-order
    unsigned long long m = ((unsigned long long)mw[wid][lane][1] << 32) |
                           (unsigned long long)mw[wid][lane][0];
    msave[b] = m;                                 // mask of tokens with expert==lane
    cnt += (unsigned)__popcll(m);
  }
  cnts[wid][lane] = cnt;
  float gs = 0.f;                                 // parallel gpart reduction
  for (int b2 = wid * 16; b2 < wid * 16 + 16; ++b2) gs += gpart[b2 * 64 + lane];
  gred[wid][lane] = gs;
  __syncthreads();
  if (wid == 0) {
    unsigned int run = 0;
#pragma unroll
    for (int w2 = 0; w2 < 16; ++w2) { base[w2][lane] = run; run += cnts[w2][lane]; }
    float g2 = 0.f;
#pragma unroll
    for (int w2 = 0; w2 < 16; ++w2) g2 += gred[w2][lane];
    float contrib = g2 * (float)run;              // gate_sum[e] * count[e]
#pragma unroll
    for (int o = 32; o > 0; o >>= 1) contrib += __shfl_xor(contrib, o);
    if (lane == 0) out0[0] = contrib * (float)NE / ((float)TOK * (float)TOK);
  }
  __syncthreads();
  unsigned int run = 0;                           // per-wave running count, lane=expert
#pragma unroll
  for (int b = 0; b < 8; ++b) {
    int ee = e[b];
    unsigned long long m = msave[b];
    unsigned int run_e = (unsigned int)__shfl((int)run, ee);
    unsigned long long m_e =
        (((unsigned long long)(unsigned int)__shfl((int)(m >> 32), ee)) << 32) |
        (unsigned long long)(unsigned int)__shfl((int)(m & 0xffffffffu), ee);
    unsigned int pos = base[wid][ee] + run_e +
                       (unsigned)__popcll(m_e & ((1ull << lane) - 1ull));
    int tok = wid * 512 + b * 64 + lane;
    code[tok] = (pos < CAP) ? (ee * CAP + (int)pos) : -1;
    run += (unsigned)__popcll(m);
  }
}

// ---------------- k3s: scatter combine (all toks) + mask (toks 0..8189) ------
__global__ __launch_bounds__(256) void k3s(float* __restrict__ out,
                                           const int* __restrict__ code,
                                           const float* __restrict__ gate) {
  int tok = blockIdx.x * 256 + threadIdx.x;       // 0..8191
  int c = code[tok];
  if (c >= 0) {
    out[1 + (long long)tok * 8192 + c] = gate[tok];
    if (tok < 8190)
      out[1 + NCOMB_LL + (long long)tok * 8192 + c] = 1.0f;
  }
}

// ---------------- k3b: last 16384 floats (mask rows 8190/8191 = scratch) -----
__global__ __launch_bounds__(256) void k3b(float* __restrict__ out, long long scr) {
  int tid = threadIdx.x;
  const int* code = (const int*)(out + scr);
  int c0 = code[8190];
  int c1 = code[8191];
  __syncthreads();                                // reads drain before overwrite
  float4 z = make_float4(0.f, 0.f, 0.f, 0.f);
  if (tid < 3) out[scr + tid] = 0.f;
  if (tid == 3) out[scr + 16383] = 0.f;
  float4* b4 = (float4*)(out + scr + 3);
  for (int i = 0; i < 16; ++i) {
    int v = tid + i * 256;
    if (v < 4095) b4[v] = z;
  }
  __syncthreads();
  long long mrow = 1 + NCOMB_LL + (long long)8190 * 8192;
  if (tid == 0 && c0 >= 0) out[mrow + c0] = 1.0f;
  if (tid == 1 && c1 >= 0) out[mrow + 8192 + c1] = 1.0f;
}

extern "C" void kernel_launch(void* const* d_in, const int* in_sizes, int n_in,
                              void* d_out, int out_size, void* d_ws, size_t ws_size,
                              hipStream_t stream) {
  const float* x = (const float*)d_in[0];
  const float* w = (const float*)d_in[1];
  float* out = (float*)d_out;

  long long scr = (long long)out_size - 16384;    // code[8192] + gate[8192] (tail)
  float* code_f = out + scr;
  float* gate   = out + scr + 8192;
  float* part   = out + scr - 2097152;            // [4][8192][64] split-K partials
  float* gpart  = part - 16384;                   // [256][64] gate-sum partials
  float* eidxf  = gpart - 8192;                   // int expert idx [8192]
  long long wtoff = ((scr - 2097152 - 16384 - 8192 - 262144) & ~3LL);  // 16B align
  float* wt = out + wtoff;                        // transposed w, 262144 floats

  // ORDER MATTERS: memset must run AFTER k2 (scratch wt/part/gpart/eidx live
  // inside the mask output region and must be erased by it — r8 bug), and
  // BEFORE k3s/k3b (which patch the zeroed canvas).
  hipLaunchKernelGGL(kwarm,   dim3(2048), dim3(256),  0, stream, x);
  hipLaunchKernelGGL(k0_wt,   dim3(1024), dim3(256),  0, stream, w, wt);
  hipLaunchKernelGGL(k1_gemm, dim3(1024), dim3(256),  0, stream, x, wt, part);
  hipLaunchKernelGGL(k1b,     dim3(256),  dim3(256),  0, stream, part, (int*)eidxf, gate, gpart);
  hipLaunchKernelGGL(k2,      dim3(1),    dim3(1024), 0, stream, (const int*)eidxf, gpart, (int*)code_f, out);
  hipMemsetAsync(out + 1, 0, (size_t)(scr - 1) * sizeof(float), stream);
  hipLaunchKernelGGL(k3s,     dim3(32),   dim3(256),  0, stream, out, (const int*)code_f, gate);
  hipLaunchKernelGGL(k3b,     dim3(1),    dim3(256),  0, stream, out, scr);
}